// Round 1
// baseline (580.393 us; speedup 1.0000x reference)
//
#include <hip/hip_runtime.h>
#include <stdint.h>

#define B_DIM 4096
#define DIN   2048
#define UNITS 2048
#define KDIM  4096   // DIN + UNITS
#define BK    64     // k per LDS tile
#define BM    256
#define BN    256    // 4 gates x 64 units

using s8v = __attribute__((ext_vector_type(8))) short;   // 8 x bf16 (4 VGPRs)
using f4v = __attribute__((ext_vector_type(4))) float;   // 4 x f32 acc

__device__ __forceinline__ unsigned short f2bf(float f) {
    union { float f; unsigned u; } v; v.f = f;
    unsigned u = v.u;
    unsigned r = u + 0x7FFFu + ((u >> 16) & 1u);   // RNE
    return (unsigned short)(r >> 16);
}

__device__ __forceinline__ void gl2lds16(const unsigned short* g, unsigned short* l) {
    __builtin_amdgcn_global_load_lds(
        (const __attribute__((address_space(1))) unsigned int*)g,
        (__attribute__((address_space(3))) unsigned int*)l, 16, 0, 0);
}

// ---------------- fused pack: z = [x|h] -> bf16, W -> bf16 transposed ----------------
// blocks [0, 8192): pack_z. blocks [8192, 16384): pack_w.  (unchanged this round)
#define NZ_BLOCKS 8192
__global__ __launch_bounds__(256) void pack_all(
    const float* __restrict__ x, const float* __restrict__ h,
    const float* __restrict__ Wf, const float* __restrict__ Wi,
    const float* __restrict__ Wc, const float* __restrict__ Wo,
    unsigned short* __restrict__ zA, unsigned short* __restrict__ WB) {
    __shared__ unsigned short T[64][68];   // +4 pad breaks bank collisions
    int t = threadIdx.x;
    int b = blockIdx.x;
    if (b < NZ_BLOCKS) {
        int ch  = b * 256 + t;              // 8-elem chunks, 512/row
        int m   = ch >> 9;
        int pos = (ch & 511) * 8;
        const float* src = (pos < DIN) ? (x + (size_t)m * DIN + pos)
                                       : (h + (size_t)m * UNITS + (pos - DIN));
        float4 v0 = *(const float4*)(src);
        float4 v1 = *(const float4*)(src + 4);
        s8v o;
        o[0]=f2bf(v0.x); o[1]=f2bf(v0.y); o[2]=f2bf(v0.z); o[3]=f2bf(v0.w);
        o[4]=f2bf(v1.x); o[5]=f2bf(v1.y); o[6]=f2bf(v1.z); o[7]=f2bf(v1.w);
        *(s8v*)(zA + (size_t)ch * 8) = o;
        return;
    }
    int bb = b - NZ_BLOCKS;
    int g   = bb >> 11;           // 2048 blocks per gate
    int rem = bb & 2047;
    int kt  = rem & 63, ut = rem >> 6;
    const float* Wg = (g == 0) ? Wf : (g == 1) ? Wi : (g == 2) ? Wc : Wo;
    int k0 = kt * 64, u0 = ut * 64;
    #pragma unroll
    for (int p = 0; p < 4; ++p) {
        int kl = p * 16 + (t >> 4);
        int ul = (t & 15) * 4;
        float4 v = *(const float4*)(Wg + (size_t)(k0 + kl) * UNITS + u0 + ul);
        T[kl][ul+0] = f2bf(v.x); T[kl][ul+1] = f2bf(v.y);
        T[kl][ul+2] = f2bf(v.z); T[kl][ul+3] = f2bf(v.w);
    }
    __syncthreads();
    #pragma unroll
    for (int p = 0; p < 2; ++p) {
        int s  = p * 256 + t;
        int ul = s >> 3;
        int kl = (s & 7) * 8;
        s8v o;
        #pragma unroll
        for (int j = 0; j < 8; ++j) o[j] = (short)T[kl + j][ul];
        *(s8v*)(WB + (size_t)(g * UNITS + u0 + ul) * KDIM + k0 + kl) = o;
    }
}

// ---------------- 256^2-tile 8-wave phase-pipelined GEMM + LSTM epilogue ----------------
// Tile: 256 m x 256 n (n = 4 gates x 64 u). 8 waves: wm(2) x wn(4); wave owns 128m x 64n
// (gate == wn). BK=64, double-buffered LDS 128 KiB, k-half-major layout:
//   A: [buf][kh][256 r][4 chunks][16B]  (16 KiB per (buf,kh) region), B same at +16384 ushorts.
//   Swizzle: physical chunk = logical ^ (r&3); applied on pre-swizzled global src (linear
//   global_load_lds dest) and on ds_read offsets -> conflict-free b128 reads.
// K-loop: 4 phases per K-tile, phase=(kh, mq): {ds_read frags | stage 1 half-tile of t+1}
//   -> s_barrier -> lgkmcnt(0)+sched_barrier(0) -> setprio(1) 16 MFMA setprio(0);
//   counted s_waitcnt vmcnt(4) only at ends of phases 1 and 3 (loads span barriers).
__global__ __launch_bounds__(512, 2) void lstm_gemm(
    const unsigned short* __restrict__ zA,   // 4096 x 4096 bf16
    const unsigned short* __restrict__ WB,   // 8192 x 4096 bf16, row n = g*2048+u
    const float* __restrict__ cin,
    const float* __restrict__ bfp, const float* __restrict__ bip,
    const float* __restrict__ bcp, const float* __restrict__ bop,
    float* __restrict__ out) {
    extern __shared__ unsigned short SMu[];   // 131072 B

    const int t    = threadIdx.x;
    const int lane = t & 63;
    const int wave = t >> 6;       // 0..7
    const int wm   = wave >> 2;    // 0..1  (m half)
    const int wn   = wave & 3;     // 0..3  (gate)
    const int fr   = lane & 15;
    const int q    = lane >> 4;

    // XCD-aware bijective swizzle (512 wgs, 8 XCDs, m-fast within XCD)
    int bid = blockIdx.x;
    int wg  = (bid & 7) * 64 + (bid >> 3);
    const int m0 = (wg & 15) * BM;
    const int u0 = (wg >> 4) * 64;

    // ---- staging assignment: per half-tile 1024 slots; thread owns slots t and t+512 ----
    const int r  = t >> 2;                       // row 0..127 (slot1: +128)
    const int c2 = (t & 3) ^ (r & 3);            // pre-swizzled logical chunk
    const unsigned short* gA0 = zA + (size_t)(m0 + r) * KDIM + c2 * 8;
    const unsigned short* gB0 = WB + (size_t)((r >> 6) * UNITS + u0 + (r & 63)) * KDIM + c2 * 8;
    const int dst0 = t * 8;                      // ushort offsets within 8192-ushort region
    const int dst1 = (t + 512) * 8;

    // ---- fragment read offsets (ushorts), same swizzle ----
    const int swz  = (q ^ (fr & 3)) * 8;
    const int aoff = (wm * 128 + fr) * 32 + swz;           // + i*512 + kh*8192 + buf*32768
    const int boff = 16384 + (wn * 64 + fr) * 32 + swz;    // + j*512 + kh*8192 + buf*32768

    f4v acc[8][4];
    #pragma unroll
    for (int i = 0; i < 8; ++i)
        #pragma unroll
        for (int j = 0; j < 4; ++j) acc[i][j] = (f4v){0.f, 0.f, 0.f, 0.f};

#define STAGE_A(khv) do { \
    gl2lds16(gA0 + ko + (khv)*32, nxt + (khv)*8192 + dst0); \
    gl2lds16(gA0 + (size_t)128*KDIM + ko + (khv)*32, nxt + (khv)*8192 + dst1); } while(0)
#define STAGE_B(khv) do { \
    gl2lds16(gB0 + ko + (khv)*32, nxt + 16384 + (khv)*8192 + dst0); \
    gl2lds16(gB0 + (size_t)2*UNITS*KDIM + ko + (khv)*32, nxt + 16384 + (khv)*8192 + dst1); } while(0)
#define LDB4(khv) { _Pragma("unroll") for (int jj = 0; jj < 4; ++jj) \
    b[jj] = *(const s8v*)(cur + boff + (khv)*8192 + jj*512); }
#define LDA4(khv, mqv) { _Pragma("unroll") for (int ii = 0; ii < 4; ++ii) \
    a[ii] = *(const s8v*)(cur + aoff + (khv)*8192 + ((mqv)*4+ii)*512); }
#define MFMA16(mqv) { _Pragma("unroll") for (int ii = 0; ii < 4; ++ii) \
    _Pragma("unroll") for (int jj = 0; jj < 4; ++jj) \
    acc[(mqv)*4+ii][jj] = __builtin_amdgcn_mfma_f32_16x16x32_bf16(a[ii], b[jj], acc[(mqv)*4+ii][jj], 0, 0, 0); }
#define BAR()  __builtin_amdgcn_s_barrier()
#define LGK0() do { asm volatile("s_waitcnt lgkmcnt(0)" ::: "memory"); \
                    __builtin_amdgcn_sched_barrier(0); } while(0)
#define VM(n)  asm volatile("s_waitcnt vmcnt(" #n ")" ::: "memory")

    // ---- prologue: stage tile 0 into buf 0 (issue order = consume order) ----
    {
        unsigned short* nxt = SMu;
        const int ko = 0;
        STAGE_A(0); STAGE_B(0);
        __builtin_amdgcn_sched_barrier(0);
        STAGE_A(1); STAGE_B(1);
        __builtin_amdgcn_sched_barrier(0);
    }
    VM(4);          // A_k0(0), B_k0(0) landed; k1 halves stay in flight
    BAR();

    s8v a[4], b[4];
    #pragma unroll 1
    for (int kt = 0; kt < 63; ++kt) {
        const unsigned short* cur = SMu + ((kt & 1) << 15);
        unsigned short* nxt = SMu + (((kt & 1) ^ 1) << 15);
        const int ko = (kt + 1) * BK;
        // phase 0: (kh0, mq0) | stage A_k0(t+1)
        LDB4(0); LDA4(0, 0); STAGE_A(0);
        BAR(); LGK0();
        __builtin_amdgcn_s_setprio(1); MFMA16(0); __builtin_amdgcn_s_setprio(0);
        BAR();
        // phase 1: (kh0, mq1) | stage B_k0(t+1) | vmcnt(4): k1(t) halves landed
        LDA4(0, 1); STAGE_B(0);
        BAR(); LGK0();
        __builtin_amdgcn_s_setprio(1); MFMA16(1); __builtin_amdgcn_s_setprio(0);
        VM(4);
        BAR();
        // phase 2: (kh1, mq0) | stage A_k1(t+1)
        LDB4(1); LDA4(1, 0); STAGE_A(1);
        BAR(); LGK0();
        __builtin_amdgcn_s_setprio(1); MFMA16(0); __builtin_amdgcn_s_setprio(0);
        BAR();
        // phase 3: (kh1, mq1) | stage B_k1(t+1) | vmcnt(4): k0(t+1) halves landed
        LDA4(1, 1); STAGE_B(1);
        BAR(); LGK0();
        __builtin_amdgcn_s_setprio(1); MFMA16(1); __builtin_amdgcn_s_setprio(0);
        VM(4);
        BAR();
    }
    // ---- tail: tile 63, no staging ----
    {
        const unsigned short* cur = SMu + ((63 & 1) << 15);
        LDB4(0); LDA4(0, 0);
        BAR(); LGK0();
        __builtin_amdgcn_s_setprio(1); MFMA16(0); __builtin_amdgcn_s_setprio(0);
        BAR();
        LDA4(0, 1);
        BAR(); LGK0();
        __builtin_amdgcn_s_setprio(1); MFMA16(1); __builtin_amdgcn_s_setprio(0);
        VM(0);
        BAR();
        LDB4(1); LDA4(1, 0);
        BAR(); LGK0();
        __builtin_amdgcn_s_setprio(1); MFMA16(0); __builtin_amdgcn_s_setprio(0);
        BAR();
        LDA4(1, 1);
        BAR(); LGK0();
        __builtin_amdgcn_s_setprio(1); MFMA16(1); __builtin_amdgcn_s_setprio(0);
        BAR();
    }

    // ---- fused epilogue: 4 chunks of 64 m-rows through padded f32 LDS ----
    float* E = (float*)SMu;
    const int EW = 260;                    // pad: (row*260+col)%32 spreads q-rows -> no conflicts
    const int du = lane;
    float bF = bfp[u0 + du], bI = bip[u0 + du], bG = bcp[u0 + du], bO = bop[u0 + du];
    float* outh = out;
    float* outc = out + (size_t)B_DIM * UNITS;
    #pragma unroll 1
    for (int chk = 0; chk < 4; ++chk) {
        if (wm == (chk >> 1)) {
            const int i0 = (chk & 1) * 4;
            #pragma unroll
            for (int ii = 0; ii < 4; ++ii)
                #pragma unroll
                for (int j = 0; j < 4; ++j) {
                    int col = wn * 64 + j * 16 + fr;
                    #pragma unroll
                    for (int p = 0; p < 4; ++p)
                        E[(ii * 16 + q * 4 + p) * EW + col] = acc[i0 + ii][j][p];
                }
        }
        __syncthreads();
        #pragma unroll
        for (int v = 0; v < 8; ++v) {
            int rloc = v * 8 + wave;
            float F = E[rloc * EW +       du] + bF;
            float I = E[rloc * EW +  64 + du] + bI;
            float G = E[rloc * EW + 128 + du] + bG;
            float O = E[rloc * EW + 192 + du] + bO;
            int m = m0 + chk * 64 + rloc;
            size_t off = (size_t)m * UNITS + u0 + du;
            float cv = cin[off];
            float fg = 1.f / (1.f + __expf(-F));
            float ig = 1.f / (1.f + __expf(-I));
            float gg = 1.f - 2.f / (1.f + __expf(2.f * G));   // tanh, inf-safe
            float og = 1.f / (1.f + __expf(-O));
            float nc = fg * cv + ig * gg;
            float nh = og * (1.f - 2.f / (1.f + __expf(2.f * nc)));
            outc[off] = nc;
            outh[off] = nh;
        }
        __syncthreads();
    }
}

extern "C" void kernel_launch(void* const* d_in, const int* in_sizes, int n_in,
                              void* d_out, int out_size, void* d_ws, size_t ws_size,
                              hipStream_t stream) {
    const float* x  = (const float*)d_in[0];
    const float* h  = (const float*)d_in[1];
    const float* c  = (const float*)d_in[2];
    const float* Wf = (const float*)d_in[3];
    const float* bf = (const float*)d_in[4];
    const float* Wi = (const float*)d_in[5];
    const float* bi = (const float*)d_in[6];
    const float* Wc = (const float*)d_in[7];
    const float* bc = (const float*)d_in[8];
    const float* Wo = (const float*)d_in[9];
    const float* bo = (const float*)d_in[10];

    unsigned short* zA = (unsigned short*)d_ws;                 // 32 MB
    unsigned short* WB = zA + (size_t)B_DIM * KDIM;             // 64 MB

    hipFuncSetAttribute(reinterpret_cast<const void*>(lstm_gemm),
                        hipFuncAttributeMaxDynamicSharedMemorySize, 131072);

    pack_all<<<2 * NZ_BLOCKS, 256, 0, stream>>>(x, h, Wf, Wi, Wc, Wo, zA, WB);
    lstm_gemm<<<dim3(512), 512, 131072, stream>>>(
        zA, WB, c, bf, bi, bc, bo, (float*)d_out);
}

// Round 2
// 488.085 us; speedup vs baseline: 1.1891x; 1.1891x over previous
//
#include <hip/hip_runtime.h>
#include <stdint.h>

#define B_DIM 4096
#define DIN   2048
#define UNITS 2048
#define KDIM  4096   // DIN + UNITS
#define BK    64     // k per LDS tile
#define BM    256
#define BN    256    // 4 gates x 64 units

using s8v = __attribute__((ext_vector_type(8))) short;   // 8 x bf16 (4 VGPRs)
using f4v = __attribute__((ext_vector_type(4))) float;   // 4 x f32 acc

__device__ __forceinline__ unsigned short f2bf(float f) {
    union { float f; unsigned u; } v; v.f = f;
    unsigned u = v.u;
    unsigned r = u + 0x7FFFu + ((u >> 16) & 1u);   // RNE
    return (unsigned short)(r >> 16);
}

__device__ __forceinline__ void gl2lds16(const unsigned short* g, unsigned short* l) {
    __builtin_amdgcn_global_load_lds(
        (const __attribute__((address_space(1))) unsigned int*)g,
        (__attribute__((address_space(3))) unsigned int*)l, 16, 0, 0);
}

// ---------------- fused pack: z = [x|h] -> bf16, W -> bf16 transposed ----------------
#define NZ_BLOCKS 8192
__global__ __launch_bounds__(256) void pack_all(
    const float* __restrict__ x, const float* __restrict__ h,
    const float* __restrict__ Wf, const float* __restrict__ Wi,
    const float* __restrict__ Wc, const float* __restrict__ Wo,
    unsigned short* __restrict__ zA, unsigned short* __restrict__ WB) {
    __shared__ unsigned short T[64][68];   // +4 pad breaks bank collisions
    int t = threadIdx.x;
    int b = blockIdx.x;
    if (b < NZ_BLOCKS) {
        int ch  = b * 256 + t;              // 8-elem chunks, 512/row
        int m   = ch >> 9;
        int pos = (ch & 511) * 8;
        const float* src = (pos < DIN) ? (x + (size_t)m * DIN + pos)
                                       : (h + (size_t)m * UNITS + (pos - DIN));
        float4 v0 = *(const float4*)(src);
        float4 v1 = *(const float4*)(src + 4);
        s8v o;
        o[0]=f2bf(v0.x); o[1]=f2bf(v0.y); o[2]=f2bf(v0.z); o[3]=f2bf(v0.w);
        o[4]=f2bf(v1.x); o[5]=f2bf(v1.y); o[6]=f2bf(v1.z); o[7]=f2bf(v1.w);
        *(s8v*)(zA + (size_t)ch * 8) = o;
        return;
    }
    int bb = b - NZ_BLOCKS;
    int g   = bb >> 11;           // 2048 blocks per gate
    int rem = bb & 2047;
    int kt  = rem & 63, ut = rem >> 6;
    const float* Wg = (g == 0) ? Wf : (g == 1) ? Wi : (g == 2) ? Wc : Wo;
    int k0 = kt * 64, u0 = ut * 64;
    #pragma unroll
    for (int p = 0; p < 4; ++p) {
        int kl = p * 16 + (t >> 4);
        int ul = (t & 15) * 4;
        float4 v = *(const float4*)(Wg + (size_t)(k0 + kl) * UNITS + u0 + ul);
        T[kl][ul+0] = f2bf(v.x); T[kl][ul+1] = f2bf(v.y);
        T[kl][ul+2] = f2bf(v.z); T[kl][ul+3] = f2bf(v.w);
    }
    __syncthreads();
    #pragma unroll
    for (int p = 0; p < 2; ++p) {
        int s  = p * 256 + t;
        int ul = s >> 3;
        int kl = (s & 7) * 8;
        s8v o;
        #pragma unroll
        for (int j = 0; j < 8; ++j) o[j] = (short)T[kl + j][ul];
        *(s8v*)(WB + (size_t)(g * UNITS + u0 + ul) * KDIM + k0 + kl) = o;
    }
}

// ---------------- 256^2-tile 8-wave phase-pipelined GEMM + LSTM epilogue ----------------
// LDS per (buf,kh,matrix) region: 128 lines x 128 B; line L holds rows {2L,2L+1} of the
// 32-bf16 kh-half. Logical slot slog = (row&1)*4 + chunk; physical slot = slog ^ (L&7).
// 3-bit XOR -> every 16-lane ds_read_b128 batch spreads 2 lanes/slot over all 8 slot
// positions = conflict-free. Staging dest is linear (global_load_lds); the inverse
// swizzle is applied to the per-thread GLOBAL source row/chunk (both-sides pattern).
__global__ __launch_bounds__(512, 2) void lstm_gemm(
    const unsigned short* __restrict__ zA,   // 4096 x 4096 bf16
    const unsigned short* __restrict__ WB,   // 8192 x 4096 bf16, row n = g*2048+u
    const float* __restrict__ cin,
    const float* __restrict__ bfp, const float* __restrict__ bip,
    const float* __restrict__ bcp, const float* __restrict__ bop,
    float* __restrict__ out) {
    extern __shared__ unsigned short SMu[];   // 131072 B

    const int t    = threadIdx.x;
    const int lane = t & 63;
    const int wave = t >> 6;       // 0..7
    const int wm   = wave >> 2;    // 0..1  (m half)
    const int wn   = wave & 3;     // 0..3  (gate)
    const int fr   = lane & 15;
    const int q    = lane >> 4;

    // XCD-aware bijective swizzle (512 wgs, 8 XCDs, m-fast within XCD)
    int bid = blockIdx.x;
    int wg  = (bid & 7) * 64 + (bid >> 3);
    const int m0 = (wg & 15) * BM;
    const int u0 = (wg >> 4) * 64;

    // ---- staging: slots s = t and t+512 per region; slot -> (line, phys slot) ----
    // s+512 differs only by +64 lines (L&7 unchanged) -> row +128, same chunk.
    const int L    = t >> 3;
    const int p    = t & 7;
    const int slog = p ^ (L & 7);
    const int rr   = 2 * L + (slog >> 2);    // row 0..127
    const int ch   = slog & 3;               // 8-bf16 chunk within kh-half
    const unsigned short* gA0 = zA + (size_t)(m0 + rr) * KDIM + ch * 8;
    const unsigned short* gB0 = WB + (size_t)((rr >> 6) * UNITS + u0 + (rr & 63)) * KDIM + ch * 8;
    const int dst0 = t * 8;                  // ushort offsets, linear
    const int dst1 = (t + 512) * 8;

    // ---- fragment read offsets (ushorts) ----
    // row RB+fr -> line (RB+fr)>>1, phys slot ((fr&1)*4+q)^(fr>>1)  (RB mult of 16)
    const int fh      = fr >> 1;
    const int laneoff = fh * 64 + ((((fr & 1) << 2) | q) ^ fh) * 8;
    const int aoff = wm * 4096 + laneoff;            // + (mq*4+ii)*512 + kh*8192 + buf*32768
    const int boff = 16384 + wn * 2048 + laneoff;    // + jj*512       + kh*8192 + buf*32768

    f4v acc[8][4];
    #pragma unroll
    for (int i = 0; i < 8; ++i)
        #pragma unroll
        for (int j = 0; j < 4; ++j) acc[i][j] = (f4v){0.f, 0.f, 0.f, 0.f};

#define STAGE_A(khv) do { \
    gl2lds16(gA0 + ko + (khv)*32, nxt + (khv)*8192 + dst0); \
    gl2lds16(gA0 + (size_t)128*KDIM + ko + (khv)*32, nxt + (khv)*8192 + dst1); } while(0)
#define STAGE_B(khv) do { \
    gl2lds16(gB0 + ko + (khv)*32, nxt + 16384 + (khv)*8192 + dst0); \
    gl2lds16(gB0 + (size_t)2*UNITS*KDIM + ko + (khv)*32, nxt + 16384 + (khv)*8192 + dst1); } while(0)
#define LDB4(khv) { _Pragma("unroll") for (int jj = 0; jj < 4; ++jj) \
    b[jj] = *(const s8v*)(cur + boff + (khv)*8192 + jj*512); }
#define LDA4(khv, mqv) { _Pragma("unroll") for (int ii = 0; ii < 4; ++ii) \
    a[ii] = *(const s8v*)(cur + aoff + (khv)*8192 + ((mqv)*4+ii)*512); }
#define MFMA16(mqv) { _Pragma("unroll") for (int ii = 0; ii < 4; ++ii) \
    _Pragma("unroll") for (int jj = 0; jj < 4; ++jj) \
    acc[(mqv)*4+ii][jj] = __builtin_amdgcn_mfma_f32_16x16x32_bf16(a[ii], b[jj], acc[(mqv)*4+ii][jj], 0, 0, 0); }
#define BAR()  __builtin_amdgcn_s_barrier()
#define LGK0() do { asm volatile("s_waitcnt lgkmcnt(0)" ::: "memory"); \
                    __builtin_amdgcn_sched_barrier(0); } while(0)
#define VM(n)  asm volatile("s_waitcnt vmcnt(" #n ")" ::: "memory")

    // ---- prologue: stage tile 0 into buf 0 (issue order = consume order) ----
    {
        unsigned short* nxt = SMu;
        const int ko = 0;
        STAGE_A(0); STAGE_B(0);
        __builtin_amdgcn_sched_barrier(0);
        STAGE_A(1); STAGE_B(1);
        __builtin_amdgcn_sched_barrier(0);
    }
    VM(4);          // A_k0(0), B_k0(0) landed; k1 halves stay in flight
    BAR();

    s8v a[4], b[4];
    #pragma unroll 1
    for (int kt = 0; kt < 63; ++kt) {
        const unsigned short* cur = SMu + ((kt & 1) << 15);
        unsigned short* nxt = SMu + (((kt & 1) ^ 1) << 15);
        const int ko = (kt + 1) * BK;
        // phase 0: (kh0, mq0) | stage A_k0(t+1)
        LDB4(0); LDA4(0, 0); STAGE_A(0);
        BAR(); LGK0();
        __builtin_amdgcn_s_setprio(1); MFMA16(0); __builtin_amdgcn_s_setprio(0);
        BAR();
        // phase 1: (kh0, mq1) | stage B_k0(t+1) | vmcnt(4): k1(t) halves landed
        LDA4(0, 1); STAGE_B(0);
        BAR(); LGK0();
        __builtin_amdgcn_s_setprio(1); MFMA16(1); __builtin_amdgcn_s_setprio(0);
        VM(4);
        BAR();
        // phase 2: (kh1, mq0) | stage A_k1(t+1)
        LDB4(1); LDA4(1, 0); STAGE_A(1);
        BAR(); LGK0();
        __builtin_amdgcn_s_setprio(1); MFMA16(0); __builtin_amdgcn_s_setprio(0);
        BAR();
        // phase 3: (kh1, mq1) | stage B_k1(t+1) | vmcnt(4): k0(t+1) halves landed
        LDA4(1, 1); STAGE_B(1);
        BAR(); LGK0();
        __builtin_amdgcn_s_setprio(1); MFMA16(1); __builtin_amdgcn_s_setprio(0);
        VM(4);
        BAR();
    }
    // ---- tail: tile 63, no staging ----
    {
        const unsigned short* cur = SMu + ((63 & 1) << 15);
        LDB4(0); LDA4(0, 0);
        BAR(); LGK0();
        __builtin_amdgcn_s_setprio(1); MFMA16(0); __builtin_amdgcn_s_setprio(0);
        BAR();
        LDA4(0, 1);
        BAR(); LGK0();
        __builtin_amdgcn_s_setprio(1); MFMA16(1); __builtin_amdgcn_s_setprio(0);
        VM(0);
        BAR();
        LDB4(1); LDA4(1, 0);
        BAR(); LGK0();
        __builtin_amdgcn_s_setprio(1); MFMA16(0); __builtin_amdgcn_s_setprio(0);
        BAR();
        LDA4(1, 1);
        BAR(); LGK0();
        __builtin_amdgcn_s_setprio(1); MFMA16(1); __builtin_amdgcn_s_setprio(0);
        BAR();
    }

    // ---- fused epilogue: 4 chunks of 64 m-rows through padded f32 LDS ----
    // chk loop FULLY unrolled: all acc indices compile-time (rule #20 — runtime
    // indexing sent the whole accumulator to scratch in the previous round).
    float* E = (float*)SMu;
    const int EW = 260;                    // pad: no read/write conflicts
    const int du = lane;
    float bF = bfp[u0 + du], bI = bip[u0 + du], bG = bcp[u0 + du], bO = bop[u0 + du];
    float* outh = out;
    float* outc = out + (size_t)B_DIM * UNITS;
    #pragma unroll
    for (int chk = 0; chk < 4; ++chk) {
        if (wm == (chk >> 1)) {
            const int i0 = (chk & 1) * 4;
            #pragma unroll
            for (int ii = 0; ii < 4; ++ii)
                #pragma unroll
                for (int j = 0; j < 4; ++j) {
                    int col = wn * 64 + j * 16 + fr;
                    #pragma unroll
                    for (int pp = 0; pp < 4; ++pp)
                        E[(ii * 16 + q * 4 + pp) * EW + col] = acc[i0 + ii][j][pp];
                }
        }
        __syncthreads();
        #pragma unroll
        for (int v = 0; v < 8; ++v) {
            int rloc = v * 8 + wave;
            float F = E[rloc * EW +       du] + bF;
            float I = E[rloc * EW +  64 + du] + bI;
            float G = E[rloc * EW + 128 + du] + bG;
            float O = E[rloc * EW + 192 + du] + bO;
            int m = m0 + chk * 64 + rloc;
            size_t off = (size_t)m * UNITS + u0 + du;
            float cv = cin[off];
            float fg = 1.f / (1.f + __expf(-F));
            float ig = 1.f / (1.f + __expf(-I));
            float gg = 1.f - 2.f / (1.f + __expf(2.f * G));   // tanh, inf-safe
            float og = 1.f / (1.f + __expf(-O));
            float nc = fg * cv + ig * gg;
            float nh = og * (1.f - 2.f / (1.f + __expf(2.f * nc)));
            outc[off] = nc;
            outh[off] = nh;
        }
        __syncthreads();
    }
}

extern "C" void kernel_launch(void* const* d_in, const int* in_sizes, int n_in,
                              void* d_out, int out_size, void* d_ws, size_t ws_size,
                              hipStream_t stream) {
    const float* x  = (const float*)d_in[0];
    const float* h  = (const float*)d_in[1];
    const float* c  = (const float*)d_in[2];
    const float* Wf = (const float*)d_in[3];
    const float* bf = (const float*)d_in[4];
    const float* Wi = (const float*)d_in[5];
    const float* bi = (const float*)d_in[6];
    const float* Wc = (const float*)d_in[7];
    const float* bc = (const float*)d_in[8];
    const float* Wo = (const float*)d_in[9];
    const float* bo = (const float*)d_in[10];

    unsigned short* zA = (unsigned short*)d_ws;                 // 32 MB
    unsigned short* WB = zA + (size_t)B_DIM * KDIM;             // 64 MB

    hipFuncSetAttribute(reinterpret_cast<const void*>(lstm_gemm),
                        hipFuncAttributeMaxDynamicSharedMemorySize, 131072);

    pack_all<<<2 * NZ_BLOCKS, 256, 0, stream>>>(x, h, Wf, Wi, Wc, Wo, zA, WB);
    lstm_gemm<<<dim3(512), 512, 131072, stream>>>(
        zA, WB, c, bf, bi, bc, bo, (float*)d_out);
}